// Round 20
// baseline (61.556 us; speedup 1.0000x reference)
//
#include <hip/hip_runtime.h>
#include <hip/hip_fp16.h>

#define NB 128
#define NS 65536
#define LP 260  // LDS row pitch in u32 (half2) units: 1040B, 16B-aligned, banks +4/row

typedef float v2f __attribute__((ext_vector_type(2)));

// ---- packed f32 math (VOP3P: 2x f32 per issue) -----------------------------
__device__ __forceinline__ v2f pk_fma(v2f a, v2f b, v2f c) {
  v2f d;
  asm("v_pk_fma_f32 %0, %1, %2, %3" : "=v"(d) : "v"(a), "v"(b), "v"(c));
  return d;
}
__device__ __forceinline__ v2f pk_add(v2f a, v2f b) {
  v2f d;
  asm("v_pk_add_f32 %0, %1, %2" : "=v"(d) : "v"(a), "v"(b));
  return d;
}
__device__ __forceinline__ v2f pk_mul(v2f a, v2f b) {
  v2f d;
  asm("v_pk_mul_f32 %0, %1, %2" : "=v"(d) : "v"(a), "v"(b));
  return d;
}

// ---- VALU-pipe cross-lane helpers -----------------------------------------
template <int CTRL>
__device__ __forceinline__ float dppmov(float x) {
  return __int_as_float(__builtin_amdgcn_update_dpp(
      0, __float_as_int(x), CTRL, 0xF, 0xF, false));
}
__device__ __forceinline__ float xor4mov(float x) {
  int t = __builtin_amdgcn_update_dpp(0, __float_as_int(x), 0x104, 0xF, 0x5, false);
  t = __builtin_amdgcn_update_dpp(t, __float_as_int(x), 0x114, 0xF, 0xA, false);
  return __int_as_float(t);
}

// In-wave 256-point WHT on packed complex (re,im); zero DS-pipe ops.
// Element e = 4*lane + q. xor1 quad_perm 0xB1; xor2 quad_perm 0x4E; xor4
// double-DPP row shifts; xor8 row_ror:8; xor16/32 permlane swaps (VALU).
__device__ __forceinline__ void wht256p(v2f (&p)[4], int lane) {
  const v2f M1 = {-1.f, -1.f};
  {
    v2f t;
    t = p[0]; p[0] = pk_add(t, p[1]); p[1] = pk_fma(M1, p[1], t);
    t = p[2]; p[2] = pk_add(t, p[3]); p[3] = pk_fma(M1, p[3], t);
    t = p[0]; p[0] = pk_add(t, p[2]); p[2] = pk_fma(M1, p[2], t);
    t = p[1]; p[1] = pk_add(t, p[3]); p[3] = pk_fma(M1, p[3], t);
  }
  const float s1f  = (lane & 1)  ? -1.f : 1.f;
  const float s2f  = (lane & 2)  ? -1.f : 1.f;
  const float s4f  = (lane & 4)  ? -1.f : 1.f;
  const float s8f  = (lane & 8)  ? -1.f : 1.f;
  const float s16f = (lane & 16) ? -1.f : 1.f;
  const float s32f = (lane & 32) ? -1.f : 1.f;
  const v2f s1 = {s1f, s1f}, s2 = {s2f, s2f}, s4 = {s4f, s4f};
  const v2f s8 = {s8f, s8f}, s16 = {s16f, s16f}, s32 = {s32f, s32f};
#pragma unroll
  for (int q = 0; q < 4; ++q) {
    v2f m = {dppmov<0xB1>(p[q].x), dppmov<0xB1>(p[q].y)};
    p[q] = pk_fma(s1, p[q], m);
  }
#pragma unroll
  for (int q = 0; q < 4; ++q) {
    v2f m = {dppmov<0x4E>(p[q].x), dppmov<0x4E>(p[q].y)};
    p[q] = pk_fma(s2, p[q], m);
  }
#pragma unroll
  for (int q = 0; q < 4; ++q) {
    v2f m = {xor4mov(p[q].x), xor4mov(p[q].y)};
    p[q] = pk_fma(s4, p[q], m);
  }
#pragma unroll
  for (int q = 0; q < 4; ++q) {
    v2f m = {dppmov<0x128>(p[q].x), dppmov<0x128>(p[q].y)};  // row_ror:8 == ^8
    p[q] = pk_fma(s8, p[q], m);
  }
#pragma unroll
  for (int q = 0; q < 4; ++q) {
    auto rre = __builtin_amdgcn_permlane16_swap(__float_as_uint(p[q].x),
                                                __float_as_uint(p[q].x), false, false);
    auto rim = __builtin_amdgcn_permlane16_swap(__float_as_uint(p[q].y),
                                                __float_as_uint(p[q].y), false, false);
    v2f lo = {__uint_as_float(rre[0]), __uint_as_float(rim[0])};
    v2f hi = {__uint_as_float(rre[1]), __uint_as_float(rim[1])};
    p[q] = pk_fma(s16, hi, lo);
  }
#pragma unroll
  for (int q = 0; q < 4; ++q) {
    auto rre = __builtin_amdgcn_permlane32_swap(__float_as_uint(p[q].x),
                                                __float_as_uint(p[q].x), false, false);
    auto rim = __builtin_amdgcn_permlane32_swap(__float_as_uint(p[q].y),
                                                __float_as_uint(p[q].y), false, false);
    v2f lo = {__uint_as_float(rre[0]), __uint_as_float(rim[0])};
    v2f hi = {__uint_as_float(rre[1]), __uint_as_float(rim[1])};
    p[q] = pk_fma(s32, hi, lo);
  }
}

__device__ __forceinline__ unsigned int pack2(float re, float im) {
  const __half2 h = __floats2half2_rn(re, im);
  return *reinterpret_cast<const unsigned int*>(&h);
}
__device__ __forceinline__ v2f unpack2(unsigned int u) {
  const float2 f = __half22float2(*reinterpret_cast<const __half2*>(&u));
  return (v2f){f.x, f.y};
}

// K1: A_hi = WHT·diag(ph_hi)·WHT along the hi axis. 32-lo x 256-hi tile,
// 512 threads (8 waves x 4 rows). LDS tile in fp16 complex (half2 per elem,
// 33.3 KB, stride LP=260 u32 -> <=2-way banks everywhere) -> 4 blocks/CU
// = 32 waves/CU (vs 2 blocks before). Global reads stay full 128B lines.
__global__ __launch_bounds__(512, 8) void k1_ahi(const float* __restrict__ sre,
                                                 const float* __restrict__ sim,
                                                 const float* __restrict__ thetas,
                                                 __half* __restrict__ T,
                                                 float* __restrict__ partial) {
  __shared__ unsigned int sh[32 * LP];
  __shared__ float2 phh4[64];
  __shared__ float2 phHQ[4];
  __shared__ float red[8];
  const int bid = blockIdx.x;
  const int b = bid >> 3, tile = bid & 7;
  const int lo0 = tile * 32;
  const int tid = threadIdx.x, lane = tid & 63, w = tid >> 6;
  if (tid < 64) {
    const float* tb = thetas + b * 16;
    float a = 0.f;
#pragma unroll
    for (int i = 0; i < 6; ++i)
      if ((tid >> (5 - i)) & 1) a += tb[i];
    phh4[tid] = make_float2(cosf(0.5f * a), -sinf(0.5f * a));
    if (tid < 4) {
      float aq = 0.f;
      if (tid & 1) aq += tb[7];
      if (tid & 2) aq += tb[6];
      phHQ[tid] = make_float2(cosf(0.5f * aq), -sinf(0.5f * aq));
    }
  }
  // ---- stage: 4 hi-rows/thread, full 128B lines; convert to half2 in LDS ----
  const float* pre = sre + ((size_t)b << 16);
  const float* pim = sim + ((size_t)b << 16);
  const int c = tid & 7, jr = tid >> 3;  // c: 4-lo group, jr: hi row base
  float4 vr[4], vi[4];
#pragma unroll
  for (int it = 0; it < 4; ++it) {
    const int j = jr + it * 64;
    vr[it] = *reinterpret_cast<const float4*>(pre + j * 256 + lo0 + c * 4);
    vi[it] = *reinterpret_cast<const float4*>(pim + j * 256 + lo0 + c * 4);
  }
  v2f acc2 = {0.f, 0.f};
#pragma unroll
  for (int it = 0; it < 4; ++it) {
    v2f u0 = {vr[it].x, vi[it].x}, u1 = {vr[it].y, vi[it].y};
    v2f u2 = {vr[it].z, vi[it].z}, u3 = {vr[it].w, vi[it].w};
    acc2 = pk_fma(u0, u0, acc2); acc2 = pk_fma(u1, u1, acc2);
    acc2 = pk_fma(u2, u2, acc2); acc2 = pk_fma(u3, u3, acc2);
    const int j = jr + it * 64;
    sh[(c * 4 + 0) * LP + j] = pack2(vr[it].x, vi[it].x);
    sh[(c * 4 + 1) * LP + j] = pack2(vr[it].y, vi[it].y);
    sh[(c * 4 + 2) * LP + j] = pack2(vr[it].z, vi[it].z);
    sh[(c * 4 + 3) * LP + j] = pack2(vr[it].w, vi[it].w);
  }
  float acc = acc2.x + acc2.y;
#pragma unroll
  for (int m2 = 32; m2 >= 1; m2 >>= 1) acc += __shfl_xor(acc, m2, 64);
  if (lane == 0) red[w] = acc;
  __syncthreads();
  if (tid == 0) {
    float sm = 0.f;
#pragma unroll
    for (int k = 0; k < 8; ++k) sm += red[k];
    partial[bid] = sm;
  }
  // hoisted per-(lane,q) phase factors
  const float2 p4 = phh4[lane];
  float prq[4], piq[4];
#pragma unroll
  for (int q = 0; q < 4; ++q) {
    const float2 pq = phHQ[q];
    prq[q] = p4.x * pq.x - p4.y * pq.y;
    piq[q] = p4.x * pq.y + p4.y * pq.x;
  }
  // ---- compute: wave w owns rows 4w..4w+3; b128 half2 reads, in-place ----
#pragma unroll
  for (int r = 0; r < 4; ++r) {
    const int row = w * 4 + r;
    uint4 hv = *reinterpret_cast<const uint4*>(&sh[row * LP + lane * 4]);
    v2f p[4] = {unpack2(hv.x), unpack2(hv.y), unpack2(hv.z), unpack2(hv.w)};
    wht256p(p, lane);
#pragma unroll
    for (int q = 0; q < 4; ++q) {
      const float ur = p[q].x, ui = p[q].y;
      const v2f tt = pk_mul(p[q], (v2f){prq[q], prq[q]});
      p[q].x = fmaf(-piq[q], ui, tt.x);
      p[q].y = fmaf(piq[q], ur, tt.y);
    }
    wht256p(p, lane);
    hv.x = pack2(p[0].x, p[0].y); hv.y = pack2(p[1].x, p[1].y);
    hv.z = pack2(p[2].x, p[2].y); hv.w = pack2(p[3].x, p[3].y);
    *reinterpret_cast<uint4*>(&sh[row * LP + lane * 4]) = hv;
  }
  __syncthreads();
  // ---- drain: T[b][m_hi][lo] fp16 complex; 2 threads/row -> 128B lines ----
  __half* Tb = T + ((size_t)b << 17);
  const int m = tid >> 1, h = tid & 1;
  unsigned int o[16];
#pragma unroll
  for (int t = 0; t < 16; ++t) o[t] = sh[(16 * h + t) * LP + m];
  __half* dst = Tb + ((size_t)m << 9) + (size_t)(lo0 + 16 * h) * 2;
  *reinterpret_cast<uint4*>(dst)      = make_uint4(o[0], o[1], o[2], o[3]);
  *reinterpret_cast<uint4*>(dst + 8)  = make_uint4(o[4], o[5], o[6], o[7]);
  *reinterpret_cast<uint4*>(dst + 16) = make_uint4(o[8], o[9], o[10], o[11]);
  *reinterpret_cast<uint4*>(dst + 24) = make_uint4(o[12], o[13], o[14], o[15]);
}

// K2: A_lo = WHT·diag(ph_lo)·WHT along contiguous lo axis (T fp16 complex ->
// one uint4 load per row/lane + cvt), |.|^2 * iv, permuted scatter
// out[srow[m_hi] ^ sloL[lane] ^ sloQ[q]] (lo-varying = fast orientation).
// Mapping: each XCD owns a 16-batch group; batch tiles in temporal burst.
__global__ __launch_bounds__(256, 8) void k2_alo_scatter(const __half* __restrict__ T,
                                                         const float* __restrict__ thetas,
                                                         const int* __restrict__ cnot,
                                                         const float* __restrict__ partial,
                                                         float* __restrict__ outp) {
  __shared__ float2 phl4[64];
  __shared__ float2 phLQ[4];
  __shared__ int sloL[64];
  __shared__ int tj[16];
  __shared__ int srow16[16];
  __shared__ float th[16];
  __shared__ float shinv;
  const int bid = blockIdx.x;
  const int x = bid & 7, s2i = bid >> 3;
  const int b = x * 16 + (s2i >> 4), tile = s2i & 15;
  const int tid = threadIdx.x, lane = tid & 63, w = tid >> 6;
  if (tid < 16) {
    th[tid] = thetas[b * 16 + tid];
    int v = 0;
#pragma unroll
    for (int i = 0; i < 16; ++i) v |= ((cnot[1 << i] >> tid) & 1) << i;
    tj[tid] = v;
  }
  if (tid == 0) {
    float sum = 0.f;
#pragma unroll
    for (int k = 0; k < 8; ++k) sum += partial[b * 8 + k];
    shinv = 1.0f / (sum * 4294967296.0f);  // fold 2^-32 WHT scaling + 1/norm^2
  }
  __syncthreads();
  if (tid < 64) {
    float a = 0.f;
#pragma unroll
    for (int i = 0; i < 6; ++i)
      if ((tid >> (5 - i)) & 1) a += th[8 + i];
    phl4[tid] = make_float2(cosf(0.5f * a), -sinf(0.5f * a));
    int v = 0;
#pragma unroll
    for (int bb = 0; bb < 6; ++bb)
      if ((tid >> bb) & 1) v ^= tj[2 + bb];
    sloL[tid] = v;
    if (tid < 4) {
      float aq = 0.f;
      if (tid & 1) aq += th[15];
      if (tid & 2) aq += th[14];
      phLQ[tid] = make_float2(cosf(0.5f * aq), -sinf(0.5f * aq));
    }
  }
  if (tid < 16) {
    const int mh = tile * 16 + tid;
    int v = 0;
#pragma unroll
    for (int bb = 0; bb < 8; ++bb)
      if ((mh >> bb) & 1) v ^= tj[8 + bb];
    srow16[tid] = v;
  }
  __syncthreads();
  const __half* Tb = T + ((size_t)b << 17);
  float* ob = outp + ((size_t)b << 16);
  const float iv = shinv;
  const float2 p4 = phl4[lane];
  const int sL = sloL[lane];
  const int sq1 = tj[0], sq2 = tj[1], sq3 = tj[0] ^ tj[1];
  float prq[4], piq[4];
#pragma unroll
  for (int q = 0; q < 4; ++q) {
    const float2 pq = phLQ[q];
    prq[q] = p4.x * pq.x - p4.y * pq.y;
    piq[q] = p4.x * pq.y + p4.y * pq.x;
  }
#pragma unroll
  for (int r = 0; r < 4; ++r) {
    const int rl = w * 4 + r;
    const int mh = tile * 16 + rl;
    const uint4 hv = *reinterpret_cast<const uint4*>(Tb + ((size_t)mh << 9) + lane * 8);
    v2f p[4] = {unpack2(hv.x), unpack2(hv.y), unpack2(hv.z), unpack2(hv.w)};
    wht256p(p, lane);
#pragma unroll
    for (int q = 0; q < 4; ++q) {
      const float ur = p[q].x, ui = p[q].y;
      const v2f tt = pk_mul(p[q], (v2f){prq[q], prq[q]});
      p[q].x = fmaf(-piq[q], ui, tt.x);
      p[q].y = fmaf(piq[q], ur, tt.y);
    }
    wht256p(p, lane);
    const int base = srow16[rl] ^ sL;
    const v2f m0 = pk_mul(p[0], p[0]);
    const v2f m1 = pk_mul(p[1], p[1]);
    const v2f m2 = pk_mul(p[2], p[2]);
    const v2f m3 = pk_mul(p[3], p[3]);
    ob[base]       = (m0.x + m0.y) * iv;
    ob[base ^ sq1] = (m1.x + m1.y) * iv;
    ob[base ^ sq2] = (m2.x + m2.y) * iv;
    ob[base ^ sq3] = (m3.x + m3.y) * iv;
  }
}

extern "C" void kernel_launch(void* const* d_in, const int* in_sizes, int n_in,
                              void* d_out, int out_size, void* d_ws, size_t ws_size,
                              hipStream_t stream) {
  const float* sre = (const float*)d_in[0];
  const float* sim = (const float*)d_in[1];
  const float* thetas = (const float*)d_in[2];
  const int* cnot = (const int*)d_in[3];
  float* outp = (float*)d_out;
  char* w = (char*)d_ws;
  const size_t HPLANE = (size_t)NB * NS * 2 * sizeof(__half);  // 32 MB fp16 complex
  if (ws_size < HPLANE + 8192) return;  // need 32 MB scratch + partials
  __half* T = (__half*)(w);
  float* partial = (float*)(w + HPLANE);  // 1024 floats

  hipLaunchKernelGGL(k1_ahi, dim3(1024), dim3(512), 0, stream, sre, sim, thetas, T, partial);
  hipLaunchKernelGGL(k2_alo_scatter, dim3(2048), dim3(256), 0, stream, T, thetas, cnot, partial, outp);
}

// Round 21
// 59.649 us; speedup vs baseline: 1.0320x; 1.0320x over previous
//
#include <hip/hip_runtime.h>
#include <hip/hip_fp16.h>

#define NB 128
#define NS 65536

typedef float v2f __attribute__((ext_vector_type(2)));

// ---- packed f32 math (VOP3P: 2x f32 per issue) -----------------------------
__device__ __forceinline__ v2f pk_fma(v2f a, v2f b, v2f c) {
  v2f d;
  asm("v_pk_fma_f32 %0, %1, %2, %3" : "=v"(d) : "v"(a), "v"(b), "v"(c));
  return d;
}
__device__ __forceinline__ v2f pk_add(v2f a, v2f b) {
  v2f d;
  asm("v_pk_add_f32 %0, %1, %2" : "=v"(d) : "v"(a), "v"(b));
  return d;
}
__device__ __forceinline__ v2f pk_mul(v2f a, v2f b) {
  v2f d;
  asm("v_pk_mul_f32 %0, %1, %2" : "=v"(d) : "v"(a), "v"(b));
  return d;
}

// ---- VALU-pipe cross-lane helpers -----------------------------------------
template <int CTRL>
__device__ __forceinline__ float dppmov(float x) {
  return __int_as_float(__builtin_amdgcn_update_dpp(
      0, __float_as_int(x), CTRL, 0xF, 0xF, false));
}
__device__ __forceinline__ float xor4mov(float x) {
  int t = __builtin_amdgcn_update_dpp(0, __float_as_int(x), 0x104, 0xF, 0x5, false);
  t = __builtin_amdgcn_update_dpp(t, __float_as_int(x), 0x114, 0xF, 0xA, false);
  return __int_as_float(t);
}

// In-wave 256-point WHT on packed complex (re,im); zero DS-pipe ops.
// Element e = 4*lane + q. xor1 quad_perm 0xB1; xor2 quad_perm 0x4E; xor4
// double-DPP row shifts; xor8 row_ror:8; xor16/32 permlane swaps (VALU).
__device__ __forceinline__ void wht256p(v2f (&p)[4], int lane) {
  const v2f M1 = {-1.f, -1.f};
  {
    v2f t;
    t = p[0]; p[0] = pk_add(t, p[1]); p[1] = pk_fma(M1, p[1], t);
    t = p[2]; p[2] = pk_add(t, p[3]); p[3] = pk_fma(M1, p[3], t);
    t = p[0]; p[0] = pk_add(t, p[2]); p[2] = pk_fma(M1, p[2], t);
    t = p[1]; p[1] = pk_add(t, p[3]); p[3] = pk_fma(M1, p[3], t);
  }
  const float s1f  = (lane & 1)  ? -1.f : 1.f;
  const float s2f  = (lane & 2)  ? -1.f : 1.f;
  const float s4f  = (lane & 4)  ? -1.f : 1.f;
  const float s8f  = (lane & 8)  ? -1.f : 1.f;
  const float s16f = (lane & 16) ? -1.f : 1.f;
  const float s32f = (lane & 32) ? -1.f : 1.f;
  const v2f s1 = {s1f, s1f}, s2 = {s2f, s2f}, s4 = {s4f, s4f};
  const v2f s8 = {s8f, s8f}, s16 = {s16f, s16f}, s32 = {s32f, s32f};
#pragma unroll
  for (int q = 0; q < 4; ++q) {
    v2f m = {dppmov<0xB1>(p[q].x), dppmov<0xB1>(p[q].y)};
    p[q] = pk_fma(s1, p[q], m);
  }
#pragma unroll
  for (int q = 0; q < 4; ++q) {
    v2f m = {dppmov<0x4E>(p[q].x), dppmov<0x4E>(p[q].y)};
    p[q] = pk_fma(s2, p[q], m);
  }
#pragma unroll
  for (int q = 0; q < 4; ++q) {
    v2f m = {xor4mov(p[q].x), xor4mov(p[q].y)};
    p[q] = pk_fma(s4, p[q], m);
  }
#pragma unroll
  for (int q = 0; q < 4; ++q) {
    v2f m = {dppmov<0x128>(p[q].x), dppmov<0x128>(p[q].y)};  // row_ror:8 == ^8
    p[q] = pk_fma(s8, p[q], m);
  }
#pragma unroll
  for (int q = 0; q < 4; ++q) {
    auto rre = __builtin_amdgcn_permlane16_swap(__float_as_uint(p[q].x),
                                                __float_as_uint(p[q].x), false, false);
    auto rim = __builtin_amdgcn_permlane16_swap(__float_as_uint(p[q].y),
                                                __float_as_uint(p[q].y), false, false);
    v2f lo = {__uint_as_float(rre[0]), __uint_as_float(rim[0])};
    v2f hi = {__uint_as_float(rre[1]), __uint_as_float(rim[1])};
    p[q] = pk_fma(s16, hi, lo);
  }
#pragma unroll
  for (int q = 0; q < 4; ++q) {
    auto rre = __builtin_amdgcn_permlane32_swap(__float_as_uint(p[q].x),
                                                __float_as_uint(p[q].x), false, false);
    auto rim = __builtin_amdgcn_permlane32_swap(__float_as_uint(p[q].y),
                                                __float_as_uint(p[q].y), false, false);
    v2f lo = {__uint_as_float(rre[0]), __uint_as_float(rim[0])};
    v2f hi = {__uint_as_float(rre[1]), __uint_as_float(rim[1])};
    p[q] = pk_fma(s32, hi, lo);
  }
}

// K1: A_hi = WHT·diag(ph_hi)·WHT along the hi axis. 32-lo x 256-hi tile,
// 1024 threads (16 waves x 2 rows). LDS float4-block swizzle (zero bank
// conflicts). Packed complex compute. Drain converts to fp16 complex
// (half2 per element) -> T traffic halved; full 128B lines per row.
__global__ __launch_bounds__(1024, 8) void k1_ahi(const float* __restrict__ sre,
                                                  const float* __restrict__ sim,
                                                  const float* __restrict__ thetas,
                                                  __half* __restrict__ T,
                                                  float* __restrict__ partial) {
  __shared__ float sr[32][260];
  __shared__ float si[32][260];
  __shared__ float2 phh4[64];
  __shared__ float2 phHQ[4];
  __shared__ float red[16];
  const int bid = blockIdx.x;
  const int b = bid >> 3, tile = bid & 7;
  const int lo0 = tile * 32;
  const int tid = threadIdx.x, lane = tid & 63, w = tid >> 6;
  if (tid < 64) {
    const float* tb = thetas + b * 16;
    float a = 0.f;
#pragma unroll
    for (int i = 0; i < 6; ++i)
      if ((tid >> (5 - i)) & 1) a += tb[i];
    phh4[tid] = make_float2(cosf(0.5f * a), -sinf(0.5f * a));
    if (tid < 4) {
      float aq = 0.f;
      if (tid & 1) aq += tb[7];
      if (tid & 2) aq += tb[6];
      phHQ[tid] = make_float2(cosf(0.5f * aq), -sinf(0.5f * aq));
    }
  }
  // load phase: prefetch 4 float4s, then conflict-free swizzled LDS transpose
  const float* pre = sre + ((size_t)b << 16);
  const float* pim = sim + ((size_t)b << 16);
  const int c = tid & 7, jr = tid >> 3;
  const int j0 = jr, j1 = jr + 128;
  const float4 vr0 = *reinterpret_cast<const float4*>(pre + j0 * 256 + lo0 + c * 4);
  const float4 vi0 = *reinterpret_cast<const float4*>(pim + j0 * 256 + lo0 + c * 4);
  const float4 vr1 = *reinterpret_cast<const float4*>(pre + j1 * 256 + lo0 + c * 4);
  const float4 vi1 = *reinterpret_cast<const float4*>(pim + j1 * 256 + lo0 + c * 4);
  float acc = vr0.x*vr0.x + vr0.y*vr0.y + vr0.z*vr0.z + vr0.w*vr0.w
            + vi0.x*vi0.x + vi0.y*vi0.y + vi0.z*vi0.z + vi0.w*vi0.w
            + vr1.x*vr1.x + vr1.y*vr1.y + vr1.z*vr1.z + vr1.w*vr1.w
            + vi1.x*vi1.x + vi1.y*vi1.y + vi1.z*vi1.z + vi1.w*vi1.w;
  {
    const int fs = ((c >> 1) & 3) << 2;
    const int j0s = j0 ^ fs, j1s = j1 ^ fs;
    sr[c*4+0][j0s] = vr0.x; sr[c*4+1][j0s] = vr0.y; sr[c*4+2][j0s] = vr0.z; sr[c*4+3][j0s] = vr0.w;
    si[c*4+0][j0s] = vi0.x; si[c*4+1][j0s] = vi0.y; si[c*4+2][j0s] = vi0.z; si[c*4+3][j0s] = vi0.w;
    sr[c*4+0][j1s] = vr1.x; sr[c*4+1][j1s] = vr1.y; sr[c*4+2][j1s] = vr1.z; sr[c*4+3][j1s] = vr1.w;
    si[c*4+0][j1s] = vi1.x; si[c*4+1][j1s] = vi1.y; si[c*4+2][j1s] = vi1.z; si[c*4+3][j1s] = vi1.w;
  }
#pragma unroll
  for (int m2 = 32; m2 >= 1; m2 >>= 1) acc += __shfl_xor(acc, m2, 64);
  if (lane == 0) red[w] = acc;
  __syncthreads();
  if (tid == 0) {
    float sm = 0.f;
#pragma unroll
    for (int k = 0; k < 16; ++k) sm += red[k];
    partial[bid] = sm;
  }
  // hoisted per-(lane,q) phase factors
  const float2 p4 = phh4[lane];
  float prq[4], piq[4];
#pragma unroll
  for (int q = 0; q < 4; ++q) {
    const float2 pq = phHQ[q];
    prq[q] = p4.x * pq.x - p4.y * pq.y;
    piq[q] = p4.x * pq.y + p4.y * pq.x;
  }
  // compute phase: wave w owns rows 2w, 2w+1; packed complex in registers
#pragma unroll
  for (int r = 0; r < 2; ++r) {
    const int ll = w * 2 + r;
    const int blk = lane ^ ((ll >> 3) & 3);
    const float4 a4 = *reinterpret_cast<const float4*>(&sr[ll][blk * 4]);
    const float4 b4 = *reinterpret_cast<const float4*>(&si[ll][blk * 4]);
    v2f p[4] = {{a4.x, b4.x}, {a4.y, b4.y}, {a4.z, b4.z}, {a4.w, b4.w}};
    wht256p(p, lane);
#pragma unroll
    for (int q = 0; q < 4; ++q) {
      const float ur = p[q].x, ui = p[q].y;
      const v2f tt = pk_mul(p[q], (v2f){prq[q], prq[q]});
      p[q].x = fmaf(-piq[q], ui, tt.x);
      p[q].y = fmaf(piq[q], ur, tt.y);
    }
    wht256p(p, lane);
    *reinterpret_cast<float4*>(&sr[ll][blk * 4]) =
        make_float4(p[0].x, p[1].x, p[2].x, p[3].x);
    *reinterpret_cast<float4*>(&si[ll][blk * 4]) =
        make_float4(p[0].y, p[1].y, p[2].y, p[3].y);
  }
  __syncthreads();
  // store phase: T[b][m_hi][lo] complex fp16; 4 threads/row, each covers
  // 8 lo values -> row writes one full 128B line. LDS position of (row ll,
  // hi m) is col m ^ (F(ll)<<2), F(ll) = (ll>>3)&3 = sub (const per thread).
  __half* Tb = T + ((size_t)b << 17);
  const int m = tid >> 2, sub = tid & 3;
  const int ms = m ^ (sub << 2);
  unsigned int o8[8];
#pragma unroll
  for (int t = 0; t < 8; ++t) {
    const int ll = 8 * sub + t;
    const __half2 h = __floats2half2_rn(sr[ll][ms], si[ll][ms]);
    o8[t] = *reinterpret_cast<const unsigned int*>(&h);
  }
  __half* dst = Tb + ((size_t)m << 9) + (size_t)(lo0 + 8 * sub) * 2;
  *reinterpret_cast<uint4*>(dst) = make_uint4(o8[0], o8[1], o8[2], o8[3]);
  *reinterpret_cast<uint4*>(dst + 8) = make_uint4(o8[4], o8[5], o8[6], o8[7]);
}

// K2: A_lo = WHT·diag(ph_lo)·WHT along contiguous lo axis (T fp16 complex ->
// one uint4 load per row/lane + cvt), |.|^2 * iv, permuted scatter
// out[srow[m_hi] ^ sloL[lane] ^ sloQ[q]] (lo-varying = fast orientation).
// Mapping: each XCD owns a 16-batch group; batch tiles in temporal burst.
__global__ __launch_bounds__(256, 8) void k2_alo_scatter(const __half* __restrict__ T,
                                                         const float* __restrict__ thetas,
                                                         const int* __restrict__ cnot,
                                                         const float* __restrict__ partial,
                                                         float* __restrict__ outp) {
  __shared__ float2 phl4[64];
  __shared__ float2 phLQ[4];
  __shared__ int sloL[64];
  __shared__ int tj[16];
  __shared__ int srow16[16];
  __shared__ float th[16];
  __shared__ float shinv;
  const int bid = blockIdx.x;
  const int x = bid & 7, s2i = bid >> 3;
  const int b = x * 16 + (s2i >> 4), tile = s2i & 15;
  const int tid = threadIdx.x, lane = tid & 63, w = tid >> 6;
  if (tid < 16) {
    th[tid] = thetas[b * 16 + tid];
    int v = 0;
#pragma unroll
    for (int i = 0; i < 16; ++i) v |= ((cnot[1 << i] >> tid) & 1) << i;
    tj[tid] = v;
  }
  if (tid == 0) {
    float sum = 0.f;
#pragma unroll
    for (int k = 0; k < 8; ++k) sum += partial[b * 8 + k];
    shinv = 1.0f / (sum * 4294967296.0f);  // fold 2^-32 WHT scaling + 1/norm^2
  }
  __syncthreads();
  if (tid < 64) {
    float a = 0.f;
#pragma unroll
    for (int i = 0; i < 6; ++i)
      if ((tid >> (5 - i)) & 1) a += th[8 + i];
    phl4[tid] = make_float2(cosf(0.5f * a), -sinf(0.5f * a));
    int v = 0;
#pragma unroll
    for (int bb = 0; bb < 6; ++bb)
      if ((tid >> bb) & 1) v ^= tj[2 + bb];
    sloL[tid] = v;
    if (tid < 4) {
      float aq = 0.f;
      if (tid & 1) aq += th[15];
      if (tid & 2) aq += th[14];
      phLQ[tid] = make_float2(cosf(0.5f * aq), -sinf(0.5f * aq));
    }
  }
  if (tid < 16) {
    const int mh = tile * 16 + tid;
    int v = 0;
#pragma unroll
    for (int bb = 0; bb < 8; ++bb)
      if ((mh >> bb) & 1) v ^= tj[8 + bb];
    srow16[tid] = v;
  }
  __syncthreads();
  const __half* Tb = T + ((size_t)b << 17);
  float* ob = outp + ((size_t)b << 16);
  const float iv = shinv;
  const float2 p4 = phl4[lane];
  const int sL = sloL[lane];
  const int sq1 = tj[0], sq2 = tj[1], sq3 = tj[0] ^ tj[1];
  float prq[4], piq[4];
#pragma unroll
  for (int q = 0; q < 4; ++q) {
    const float2 pq = phLQ[q];
    prq[q] = p4.x * pq.x - p4.y * pq.y;
    piq[q] = p4.x * pq.y + p4.y * pq.x;
  }
#pragma unroll
  for (int r = 0; r < 4; ++r) {
    const int rl = w * 4 + r;
    const int mh = tile * 16 + rl;
    const uint4 hv = *reinterpret_cast<const uint4*>(Tb + ((size_t)mh << 9) + lane * 8);
    const float2 f0 = __half22float2(*reinterpret_cast<const __half2*>(&hv.x));
    const float2 f1 = __half22float2(*reinterpret_cast<const __half2*>(&hv.y));
    const float2 f2 = __half22float2(*reinterpret_cast<const __half2*>(&hv.z));
    const float2 f3 = __half22float2(*reinterpret_cast<const __half2*>(&hv.w));
    v2f p[4] = {{f0.x, f0.y}, {f1.x, f1.y}, {f2.x, f2.y}, {f3.x, f3.y}};
    wht256p(p, lane);
#pragma unroll
    for (int q = 0; q < 4; ++q) {
      const float ur = p[q].x, ui = p[q].y;
      const v2f tt = pk_mul(p[q], (v2f){prq[q], prq[q]});
      p[q].x = fmaf(-piq[q], ui, tt.x);
      p[q].y = fmaf(piq[q], ur, tt.y);
    }
    wht256p(p, lane);
    const int base = srow16[rl] ^ sL;
    const v2f m0 = pk_mul(p[0], p[0]);
    const v2f m1 = pk_mul(p[1], p[1]);
    const v2f m2 = pk_mul(p[2], p[2]);
    const v2f m3 = pk_mul(p[3], p[3]);
    ob[base]       = (m0.x + m0.y) * iv;
    ob[base ^ sq1] = (m1.x + m1.y) * iv;
    ob[base ^ sq2] = (m2.x + m2.y) * iv;
    ob[base ^ sq3] = (m3.x + m3.y) * iv;
  }
}

extern "C" void kernel_launch(void* const* d_in, const int* in_sizes, int n_in,
                              void* d_out, int out_size, void* d_ws, size_t ws_size,
                              hipStream_t stream) {
  const float* sre = (const float*)d_in[0];
  const float* sim = (const float*)d_in[1];
  const float* thetas = (const float*)d_in[2];
  const int* cnot = (const int*)d_in[3];
  float* outp = (float*)d_out;
  char* w = (char*)d_ws;
  const size_t HPLANE = (size_t)NB * NS * 2 * sizeof(__half);  // 32 MB fp16 complex
  if (ws_size < HPLANE + 8192) return;  // need 32 MB scratch + partials
  __half* T = (__half*)(w);
  float* partial = (float*)(w + HPLANE);  // 1024 floats

  hipLaunchKernelGGL(k1_ahi, dim3(1024), dim3(1024), 0, stream, sre, sim, thetas, T, partial);
  hipLaunchKernelGGL(k2_alo_scatter, dim3(2048), dim3(256), 0, stream, T, thetas, cnot, partial, outp);
}